// Round 4
// baseline (409.898 us; speedup 1.0000x reference)
//
#include <hip/hip_runtime.h>
#include <stdint.h>

// Problem constants
#define BB 32
#define FO 520          // F*O
#define M1 16640        // BB*FO
#define KIN 2048        // IN
#define KA 2112         // IN + 64 (S-matrix columns folded into K)
#define N1 1024         // 2*G (concatenated rel|tem)
#define GG 512          // G
#define K2P 576         // 520 padded to mult of 64
#define M2 640          // 520 padded to mult of 64/128

typedef unsigned short u16;
typedef short v8s __attribute__((ext_vector_type(8)));   // 8 bf16 MFMA A/B frag
typedef float v4f __attribute__((ext_vector_type(4)));   // MFMA C/D frag

__device__ __forceinline__ u16 f2bf(float f) {
  union { float f; unsigned u; } v; v.f = f;
  unsigned r = v.u + 0x7fffu + ((v.u >> 16) & 1u);   // RNE, inputs finite
  return (u16)(r >> 16);
}

__device__ __forceinline__ float fast_tanh(float x) {
  float cx = fminf(fmaxf(x, -15.f), 15.f);
  float e = __expf(2.f * cx);
  return (e - 1.f) / (e + 1.f);
}

__device__ __forceinline__ void glds(const u16* g, u16* l) {
  __builtin_amdgcn_global_load_lds((const __attribute__((address_space(1))) void*)g,
                                   (__attribute__((address_space(3))) void*)l, 16, 0, 0);
}

// ---------- prep_all: A1 rows | Wc rows | A2+tsum rows, one dispatch ----------
__global__ void prep_all_kernel(const float* __restrict__ rf, const int* __restrict__ rel,
                                const float* __restrict__ relW, const float* __restrict__ temW,
                                const float* __restrict__ emb, const float* __restrict__ tem,
                                u16* __restrict__ A1, u16* __restrict__ Wc,
                                u16* __restrict__ A2, float* __restrict__ tsum) {
  const int blk = blockIdx.x;
  const int t = threadIdx.x;
  if (blk < M1 + 1024) {               // ---- A1 / Wc row (2048 f32 -> bf16, + 64 K-ext)
    const float* src;
    u16* orow;
    if (blk < M1) { src = rf + (size_t)blk * KIN; orow = A1 + (size_t)blk * KA; }
    else {
      const int n = blk - M1;
      src = (n < GG) ? (relW + (size_t)n * KIN) : (temW + (size_t)(n - GG) * KIN);
      orow = Wc + (size_t)n * KA;
    }
    const float4* p = (const float4*)src;
    float4 a = p[2 * t], b = p[2 * t + 1];
    v8s v;
    v[0] = (short)f2bf(a.x); v[1] = (short)f2bf(a.y);
    v[2] = (short)f2bf(a.z); v[3] = (short)f2bf(a.w);
    v[4] = (short)f2bf(b.x); v[5] = (short)f2bf(b.y);
    v[6] = (short)f2bf(b.z); v[7] = (short)f2bf(b.w);
    *(v8s*)(orow + t * 8) = v;
    if (t < 64) {                      // K-extension columns
      float sval = 0.f;
      if (blk < M1) {                  // S[m,l] = count(idx==l+1)/msum
        const int* rp = rel + (size_t)blk * 20;
        int cnt = 0, ms = 0;
#pragma unroll
        for (int j = 0; j < 20; ++j) { int ix = rp[j]; cnt += (ix == t + 1); ms += (ix > 0); }
        if (t < 52 && ms > 0) sval = (float)cnt / (float)ms;
      } else {
        const int n = blk - M1;
        if (n < GG && t < 52) sval = emb[(size_t)(t + 1) * GG + n];
      }
      orow[KIN + t] = f2bf(sval);
    }
    return;
  }
  // ---- casta2 part: tem_feats -> A2 [32][640][576] bf16 + row sums
  const int w = t >> 6, l = t & 63;
  const int row = (blk - (M1 + 1024)) * 4 + w;   // [32][640]
  const int b = row / M2, i = row % M2;
  u16* orow = A2 + (size_t)row * K2P;
  v8s z = {0, 0, 0, 0, 0, 0, 0, 0};
  if (i >= FO) {
    *(v8s*)(orow + l * 8) = z;
    if (l < 8) *(v8s*)(orow + (64 + l) * 8) = z;
    return;
  }
  const float* srow = tem + ((size_t)b * FO + i) * FO;
  float s = 0.f;
  {
    float4 a = *(const float4*)(srow + 8 * l);
    float4 bb = *(const float4*)(srow + 8 * l + 4);
    s += a.x + a.y + a.z + a.w + bb.x + bb.y + bb.z + bb.w;
    v8s v;
    v[0] = (short)f2bf(a.x); v[1] = (short)f2bf(a.y);
    v[2] = (short)f2bf(a.z); v[3] = (short)f2bf(a.w);
    v[4] = (short)f2bf(bb.x); v[5] = (short)f2bf(bb.y);
    v[6] = (short)f2bf(bb.z); v[7] = (short)f2bf(bb.w);
    *(v8s*)(orow + l * 8) = v;
  }
  if (l < 8) {
    if (l == 0) {
      float4 a = *(const float4*)(srow + 512);
      float4 bb = *(const float4*)(srow + 516);
      s += a.x + a.y + a.z + a.w + bb.x + bb.y + bb.z + bb.w;
      v8s v;
      v[0] = (short)f2bf(a.x); v[1] = (short)f2bf(a.y);
      v[2] = (short)f2bf(a.z); v[3] = (short)f2bf(a.w);
      v[4] = (short)f2bf(bb.x); v[5] = (short)f2bf(bb.y);
      v[6] = (short)f2bf(bb.z); v[7] = (short)f2bf(bb.w);
      *(v8s*)(orow + 512) = v;
    } else {
      *(v8s*)(orow + (64 + l) * 8) = z;
    }
  }
#pragma unroll
  for (int off = 32; off > 0; off >>= 1) s += __shfl_down(s, off);
  if (l == 0) tsum[(size_t)b * FO + i] = s;
}

// ---------- GEMM1: [16640x2112]x[2112x1024], 256(or 128)x256 tiles ----------
// Phase-split counted-vmcnt schedule (T3+T4+T5 per 8-phase template, adapted):
// 8 waves 2m x 4n, wave tile (MR*16) x 64. BK=32; 3 LDS bufs of 32KB
// (A [256][32] | B [256][32], chunk-XOR swizzled slot = c ^ ((row>>1)&3)).
// Per K-tile: 2 phases (MR=8) or 1 phase (MR=4); each phase:
//   ds_read frags | issue 2 gload_lds of tile t+2 | [vmcnt(L) at tile end]
//   barrier | lgkmcnt(0) | sched_barrier | setprio(1) | 16 MFMA | setprio(0) | barrier
// vmcnt(L) keeps tile t+2's L loads in flight while draining t+1's (issued
// 2-4 phases earlier -> latency fully covered). Never drains to 0 mid-loop.
template <int MR>
__device__ __forceinline__ void gemm1_body(
    const u16* __restrict__ A, const u16* __restrict__ Wc,
    const float* __restrict__ rel_b, const float* __restrict__ tem_b,
    const float* __restrict__ bn_w, const float* __restrict__ bn_b,
    const float* __restrict__ bn_rm, const float* __restrict__ bn_rv,
    float* __restrict__ out, u16* __restrict__ BT, u16* smem,
    const int m0, const int n0) {
  const int tid = threadIdx.x;
  const int lane = tid & 63;
  const int wv = tid >> 6;                        // 0..7
  const int wm = wv >> 2, wn = wv & 3;            // 2m x 4n
  const int quad = lane >> 4, r16 = lane & 15;
  constexpr int WM16 = MR * 16;                   // wave m-stride
  constexpr int L = 2 + MR / 4;                   // gloads per thread per K-tile

  // staging pointers (chunk c = sl ^ ((r>>1)&3) pre-swizzled at global source)
  const int r0 = tid >> 2, sl0 = tid & 3;
  const int r1 = 128 + r0;
  const u16* gb0 = Wc + (size_t)(n0 + r0) * KA + (sl0 ^ ((r0 >> 1) & 3)) * 8;
  const u16* gb1 = Wc + (size_t)(n0 + r1) * KA + (sl0 ^ ((r1 >> 1) & 3)) * 8;
  const u16* ga0 = A + (size_t)(m0 + r0) * KA + (sl0 ^ ((r0 >> 1) & 3)) * 8;
  const u16* ga1 = A + (size_t)(m0 + r1) * KA + (sl0 ^ ((r1 >> 1) & 3)) * 8;  // MR==8 only

  v4f acc[MR][4];
#pragma unroll
  for (int i = 0; i < MR; ++i)
#pragma unroll
    for (int j = 0; j < 4; ++j) { v4f z = {0.f, 0.f, 0.f, 0.f}; acc[i][j] = z; }

  // prologue: stage K-tiles 0,1 into bufs 0,1
#pragma unroll
  for (int pt = 0; pt < 2; ++pt) {
    u16* d = smem + pt * 16384;
    glds(gb0, d + 8192 + tid * 8);
    glds(gb1, d + 12288 + tid * 8);
    glds(ga0, d + tid * 8);
    if constexpr (MR == 8) glds(ga1, d + 4096 + tid * 8);
    gb0 += 32; gb1 += 32; ga0 += 32;
    if constexpr (MR == 8) ga1 += 32;
  }
  if constexpr (MR == 8) asm volatile("s_waitcnt vmcnt(4)" ::: "memory");
  else                   asm volatile("s_waitcnt vmcnt(3)" ::: "memory");
  __builtin_amdgcn_s_barrier();

  int cb = 0;
  for (int t = 0; t < 66; ++t) {
    const u16* As_ = smem + cb * 16384;
    const u16* Bs_ = As_ + 8192;
    const int sb = (cb + 2 >= 3) ? cb - 1 : cb + 2;   // (t+2)%3
    u16* sd = smem + sb * 16384;
    v8s af[4], bf[4];

    // ---- phase 0: mtt 0..3 (both MR), B frags; stage B(t+2)
#pragma unroll
    for (int i = 0; i < 4; ++i) {
      const int ra = wm * WM16 + i * 16 + r16;
      af[i] = *(const v8s*)&As_[ra * 32 + ((quad ^ ((ra >> 1) & 3)) * 8)];
      const int rb = wn * 64 + i * 16 + r16;
      bf[i] = *(const v8s*)&Bs_[rb * 32 + ((quad ^ ((rb >> 1) & 3)) * 8)];
    }
    if (t < 64) {
      glds(gb0, sd + 8192 + tid * 8);
      glds(gb1, sd + 12288 + tid * 8);
      gb0 += 32; gb1 += 32;
      if constexpr (MR == 4) {                    // single-phase tile: stage A here too
        glds(ga0, sd + tid * 8);
        ga0 += 32;
      }
    }
    if constexpr (MR == 4) {                      // tile-end wait (single phase)
      if (t < 64) asm volatile("s_waitcnt vmcnt(3)" ::: "memory");
      else        asm volatile("s_waitcnt vmcnt(0)" ::: "memory");
    }
    __builtin_amdgcn_s_barrier();
    asm volatile("s_waitcnt lgkmcnt(0)" ::: "memory");
    __builtin_amdgcn_sched_barrier(0);
    __builtin_amdgcn_s_setprio(1);
#pragma unroll
    for (int i = 0; i < 4; ++i)
#pragma unroll
      for (int j = 0; j < 4; ++j)
        acc[i][j] = __builtin_amdgcn_mfma_f32_16x16x32_bf16(af[i], bf[j], acc[i][j], 0, 0, 0);
    __builtin_amdgcn_s_setprio(0);
    __builtin_amdgcn_s_barrier();

    if constexpr (MR == 8) {
      // ---- phase 1: mtt 4..7 (bf reused in regs); stage A(t+2); tile-end vmcnt
#pragma unroll
      for (int i = 0; i < 4; ++i) {
        const int ra = wm * WM16 + (4 + i) * 16 + r16;
        af[i] = *(const v8s*)&As_[ra * 32 + ((quad ^ ((ra >> 1) & 3)) * 8)];
      }
      if (t < 64) {
        glds(ga0, sd + tid * 8);
        glds(ga1, sd + 4096 + tid * 8);
        ga0 += 32; ga1 += 32;
        asm volatile("s_waitcnt vmcnt(4)" ::: "memory");
      } else {
        asm volatile("s_waitcnt vmcnt(0)" ::: "memory");
      }
      __builtin_amdgcn_s_barrier();
      asm volatile("s_waitcnt lgkmcnt(0)" ::: "memory");
      __builtin_amdgcn_sched_barrier(0);
      __builtin_amdgcn_s_setprio(1);
#pragma unroll
      for (int i = 0; i < 4; ++i)
#pragma unroll
        for (int j = 0; j < 4; ++j)
          acc[4 + i][j] = __builtin_amdgcn_mfma_f32_16x16x32_bf16(af[i], bf[j], acc[4 + i][j], 0, 0, 0);
      __builtin_amdgcn_s_setprio(0);
      __builtin_amdgcn_s_barrier();
    }

    cb = (cb == 2) ? 0 : cb + 1;
  }

  if (n0 < GG) {        // ---- rel half: +bias, tanh, BN -> out
#pragma unroll
    for (int mtt = 0; mtt < MR; ++mtt) {
      const int mb = m0 + wm * WM16 + mtt * 16 + quad * 4;
      const int bb = mb / FO;
      const int fo0 = mb - bb * FO;               // quad never crosses batch (4 | FO)
      float inv[4], rm[4], bofs[4];
#pragma unroll
      for (int r = 0; r < 4; ++r) {
        const int fo = fo0 + r;
        inv[r] = bn_w[fo] * rsqrtf(bn_rv[fo] + 1e-5f);
        rm[r] = bn_rm[fo]; bofs[r] = bn_b[fo];
      }
#pragma unroll
      for (int ntt = 0; ntt < 4; ++ntt) {
        const int n = n0 + wn * 64 + ntt * 16 + r16;
        const float rbn = rel_b[n];
#pragma unroll
        for (int r = 0; r < 4; ++r) {
          float val = (fast_tanh(acc[mtt][ntt][r] + rbn) - rm[r]) * inv[r] + bofs[r];
          __builtin_nontemporal_store(val, out + (size_t)(mb + r) * N1 + n);
        }
      }
    }
  } else {              // ---- tem half: +bias -> bf16 -> LDS transpose -> BT
    constexpr int SP = MR * 32 + 8;               // transpose row stride (pad)
    __syncthreads();                              // K-loop LDS reads all done
#pragma unroll
    for (int p = 0; p < 4; ++p) {                 // one 64-g chunk per n-wave
      if (p) __syncthreads();
      if (wn == p) {                              // 2 writer waves (wm 0,1)
#pragma unroll
        for (int mtt = 0; mtt < MR; ++mtt) {
          const int il = wm * WM16 + mtt * 16 + quad * 4;
#pragma unroll
          for (int ntt = 0; ntt < 4; ++ntt) {
            const int gl = ntt * 16 + r16;        // 0..63 within this chunk
            const float tb = tem_b[(n0 - GG) + p * 64 + gl];
            ushort4 w;
            w.x = f2bf(acc[mtt][ntt][0] + tb);
            w.y = f2bf(acc[mtt][ntt][1] + tb);
            w.z = f2bf(acc[mtt][ntt][2] + tb);
            w.w = f2bf(acc[mtt][ntt][3] + tb);
            *(ushort4*)&smem[gl * SP + il] = w;
          }
        }
      }
      __syncthreads();
      // copy out 64 g x (MR*32) i, 8-elem contiguous chunks
      if constexpr (MR == 8) {
#pragma unroll
        for (int sp = 0; sp < 4; ++sp) {
          const int gl = sp * 16 + (tid >> 5);    // 0..63
          const int ch = tid & 31;
          const int m = m0 + ch * 8;
          const int b1 = m / FO;                  // 8-runs never cross b (520%8==0)
          const int i1 = m - b1 * FO;
          v8s val = *(const v8s*)&smem[gl * SP + ch * 8];
          const int g = (n0 - GG) + p * 64 + gl;
          *(v8s*)(BT + ((size_t)(b1 * GG + g)) * K2P + i1) = val;
        }
      } else {
#pragma unroll
        for (int sp = 0; sp < 2; ++sp) {
          const int gl = sp * 32 + (tid >> 4);    // 0..63
          const int ch = tid & 15;
          const int m = m0 + ch * 8;
          const int b1 = m / FO;
          const int i1 = m - b1 * FO;
          v8s val = *(const v8s*)&smem[gl * SP + ch * 8];
          const int g = (n0 - GG) + p * 64 + gl;
          *(v8s*)(BT + ((size_t)(b1 * GG + g)) * K2P + i1) = val;
        }
      }
    }
  }
}

__global__ __launch_bounds__(512, 2) void gemm1_kernel(
    const u16* __restrict__ A, const u16* __restrict__ Wc,
    const float* __restrict__ rel_b, const float* __restrict__ tem_b,
    const float* __restrict__ bn_w, const float* __restrict__ bn_b,
    const float* __restrict__ bn_rm, const float* __restrict__ bn_rv,
    float* __restrict__ out, u16* __restrict__ BT) {
  __shared__ u16 smem[49152];                     // 96KB: 3 x (A 16KB | B 16KB)
  const int id = blockIdx.x;
  if (id < 256) {                                 // 64 m-tiles x 4 n-tiles of 256x256
    const int wgid = (id & 7) * 32 + (id >> 3);   // XCD-chunked swizzle (256%8==0)
    const int m0 = (wgid >> 2) * 256, n0 = (wgid & 3) * 256;
    gemm1_body<8>(A, Wc, rel_b, tem_b, bn_w, bn_b, bn_rm, bn_rv, out, BT, smem, m0, n0);
  } else {                                        // tail: 2 m-tiles x 4 n of 128x256
    const int sid = id - 256;
    const int m0 = 16384 + (sid >> 2) * 128, n0 = (sid & 3) * 256;
    gemm1_body<4>(A, Wc, rel_b, tem_b, bn_w, bn_b, bn_rm, bn_rv, out, BT, smem, m0, n0);
  }
}

// ---------- GEMM2: batched [640x576]x[576x512], 128x128 tiles, depth-2 pipeline ----------
#define G2_STAGE(DST)                                                                            \
  do {                                                                                           \
    u16* dst_ = smem + (DST);                                                                    \
    glds(ga0, dst_ + lofA0); glds(gb0, dst_ + lofB0);                                            \
    glds(ga1, dst_ + lofA1); glds(gb1, dst_ + lofB1);                                            \
    ga0 += 32; gb0 += 32; ga1 += 32; gb1 += 32;                                                  \
  } while (0)

#define G2_COMPUTE(CB)                                                                           \
  do {                                                                                           \
    const u16* As_ = smem + (CB) * 8192;                                                         \
    const u16* Bs_ = As_ + 4096;                                                                 \
    v8s af[4], bf[4];                                                                            \
    _Pragma("unroll") for (int t4 = 0; t4 < 4; ++t4) {                                           \
      const int ra = wm * 64 + t4 * 16 + r16;                                                    \
      const int rb = wn * 64 + t4 * 16 + r16;                                                    \
      af[t4] = *(const v8s*)&As_[ra * 32 + ((quad ^ ((ra >> 1) & 3)) * 8)];                      \
      bf[t4] = *(const v8s*)&Bs_[rb * 32 + ((quad ^ ((rb >> 1) & 3)) * 8)];                      \
    }                                                                                            \
    _Pragma("unroll") for (int mtt = 0; mtt < 4; ++mtt)                                          \
      _Pragma("unroll") for (int ntt = 0; ntt < 4; ++ntt)                                        \
        acc[mtt][ntt] =                                                                          \
            __builtin_amdgcn_mfma_f32_16x16x32_bf16(af[mtt], bf[ntt], acc[mtt][ntt], 0, 0, 0);   \
  } while (0)

__global__ __launch_bounds__(256) void gemm2_kernel(
    const u16* __restrict__ A2, const u16* __restrict__ BT,
    const float* __restrict__ tsum,
    const float* __restrict__ bn_w, const float* __restrict__ bn_b,
    const float* __restrict__ bn_rm, const float* __restrict__ bn_rv,
    float* __restrict__ out) {
  __shared__ u16 smem[24576];                     // 48KB: 3 bufs
  const int tid = threadIdx.x;
  const int lane = tid & 63;
  const int wv = tid >> 6, wm = wv >> 1, wn = wv & 1;   // 2x2 waves of 64x64
  const int m0 = blockIdx.x * 128;                // 5 tiles over 640
  const int n0 = blockIdx.y * 128;                // 4 tiles over 512
  const int b = blockIdx.z;
  const u16* Ab = A2 + (size_t)b * M2 * K2P;
  const u16* Bb = BT + (size_t)b * GG * K2P;
  const int quad = lane >> 4, r16 = lane & 15;

  const u16 *ga0, *ga1, *gb0, *gb1;
  {
    const int r0 = tid >> 2, sl0 = tid & 3;
    const int c0 = sl0 ^ ((r0 >> 1) & 3);
    ga0 = Ab + (size_t)(m0 + r0) * K2P + c0 * 8;
    gb0 = Bb + (size_t)(n0 + r0) * K2P + c0 * 8;
    const int L1 = 256 + tid;
    const int r1 = L1 >> 2, sl1 = L1 & 3;
    const int c1 = sl1 ^ ((r1 >> 1) & 3);
    ga1 = Ab + (size_t)(m0 + r1) * K2P + c1 * 8;
    gb1 = Bb + (size_t)(n0 + r1) * K2P + c1 * 8;
  }
  const int lofA0 = wv * 512, lofA1 = 2048 + wv * 512;
  const int lofB0 = 4096 + wv * 512, lofB1 = 6144 + wv * 512;

  v4f acc[4][4];
#pragma unroll
  for (int i = 0; i < 4; ++i)
#pragma unroll
    for (int j = 0; j < 4; ++j) { v4f z = {0.f, 0.f, 0.f, 0.f}; acc[i][j] = z; }

  // prologue
  G2_STAGE(0);
  G2_STAGE(8192);

  int cb = 0, nb = 2;
  for (int t = 0; t < 16; ++t) {                  // tiles 0..15; stages 2..17 (18 total)
    G2_STAGE(nb * 8192);
    asm volatile("s_waitcnt vmcnt(8)" ::: "memory");
    __builtin_amdgcn_s_barrier();
    G2_COMPUTE(cb);
    asm volatile("s_waitcnt lgkmcnt(0)" ::: "memory");
    __builtin_amdgcn_s_barrier();
    cb = (cb == 2) ? 0 : cb + 1;
    nb = (nb == 2) ? 0 : nb + 1;
  }
  {                                               // tiles 16, 17
    const int cb1 = (cb == 2) ? 0 : cb + 1;
    asm volatile("s_waitcnt vmcnt(4)" ::: "memory");
    __builtin_amdgcn_s_barrier();
    G2_COMPUTE(cb);
    asm volatile("s_waitcnt vmcnt(0) lgkmcnt(0)" ::: "memory");
    __builtin_amdgcn_s_barrier();
    G2_COMPUTE(cb1);
  }

  // epilogue: tem half of out
#pragma unroll
  for (int mtt = 0; mtt < 4; ++mtt) {
    const int ibase = m0 + wm * 64 + mtt * 16 + quad * 4;
    if (ibase >= FO) continue;                    // padded rows (ibase%4==0, FO%4==0)
    float ts[4], inv[4], rm[4], bofs[4];
#pragma unroll
    for (int r = 0; r < 4; ++r) {
      const int i = ibase + r;
      ts[r] = 1.f / tsum[(size_t)b * FO + i];
      inv[r] = bn_w[i] * rsqrtf(bn_rv[i] + 1e-5f);
      rm[r] = bn_rm[i]; bofs[r] = bn_b[i];
    }
#pragma unroll
    for (int ntt = 0; ntt < 4; ++ntt) {
      const int g = n0 + wn * 64 + ntt * 16 + r16;
#pragma unroll
      for (int r = 0; r < 4; ++r) {
        float val = (fast_tanh(acc[mtt][ntt][r] * ts[r]) - rm[r]) * inv[r] + bofs[r];
        __builtin_nontemporal_store(val, out + ((size_t)(b * FO + (ibase + r))) * N1 + GG + g);
      }
    }
  }
}

extern "C" void kernel_launch(void* const* d_in, const int* in_sizes, int n_in,
                              void* d_out, int out_size, void* d_ws, size_t ws_size,
                              hipStream_t stream) {
  const float* region_feats = (const float*)d_in[0];
  // d_in[1] region_masks: unused by reference
  const int* rel_feats = (const int*)d_in[2];
  const float* tem_feats = (const float*)d_in[3];
  const float* rel_W = (const float*)d_in[4];
  const float* rel_b = (const float*)d_in[5];
  const float* rel_emb = (const float*)d_in[6];
  const float* tem_W = (const float*)d_in[7];
  const float* tem_b = (const float*)d_in[8];
  const float* bn_w = (const float*)d_in[9];
  const float* bn_b = (const float*)d_in[10];
  const float* bn_rm = (const float*)d_in[11];
  const float* bn_rv = (const float*)d_in[12];
  float* out = (float*)d_out;

  // Workspace layout: total 117.1 MB
  char* base = (char*)d_ws;
  u16* A1 = (u16*)base;                                   // [16640][2112] bf16 : 70,287,360
  u16* Wc = (u16*)(base + 70287360);                      // [1024][2112] bf16  :  4,325,376
  u16* A2 = (u16*)(base + 74612736);                      // [32][640][576] bf16: 23,592,960
  u16* BT = (u16*)(base + 98205696);                      // [32][512][576] bf16: 18,874,368
  float* tsum = (float*)(base + 117080064);               // [32*520] f32       :     66,560

  prep_all_kernel<<<M1 + 1024 + 5120, 256, 0, stream>>>(
      region_feats, rel_feats, rel_W, tem_W, rel_emb, tem_feats, A1, Wc, A2, tsum);
  gemm1_kernel<<<264, 512, 0, stream>>>(A1, Wc, rel_b, tem_b,
                                        bn_w, bn_b, bn_rm, bn_rv, out, BT);
  gemm2_kernel<<<dim3(5, 4, 32), 256, 0, stream>>>(A2, BT, tsum,
                                                   bn_w, bn_b, bn_rm, bn_rv, out);
}

// Round 5
// 387.576 us; speedup vs baseline: 1.0576x; 1.0576x over previous
//
#include <hip/hip_runtime.h>
#include <stdint.h>

// Problem constants
#define BB 32
#define FO 520          // F*O
#define M1 16640        // BB*FO
#define KIN 2048        // IN
#define KA 2112         // IN + 64 (S-matrix columns folded into K)
#define N1 1024         // 2*G (concatenated rel|tem)
#define GG 512          // G
#define K2P 576         // 520 padded to mult of 64
#define M2 640          // 520 padded to mult of 64/128

typedef unsigned short u16;
typedef short v8s __attribute__((ext_vector_type(8)));   // 8 bf16 MFMA A/B frag
typedef float v4f __attribute__((ext_vector_type(4)));   // MFMA C/D frag

__device__ __forceinline__ u16 f2bf(float f) {
  union { float f; unsigned u; } v; v.f = f;
  unsigned r = v.u + 0x7fffu + ((v.u >> 16) & 1u);   // RNE, inputs finite
  return (u16)(r >> 16);
}

__device__ __forceinline__ float fast_tanh(float x) {
  float cx = fminf(fmaxf(x, -15.f), 15.f);
  float e = __expf(2.f * cx);
  return (e - 1.f) / (e + 1.f);
}

// ---------- prep_all: 512-thread blocks; 2 cast-rows or 8 casta2 rows ----------
// blocks [0, 8832): two A1/Wc rows each (read-once streams via nontemporal loads)
// blocks [8832, 11392): casta2 -> A2 [32][640][576] bf16 + tsum row sums
#define PREP_ROWS 8832   // 17664/2
__global__ __launch_bounds__(512) void prep_all_kernel(
    const float* __restrict__ rf, const int* __restrict__ rel,
    const float* __restrict__ relW, const float* __restrict__ temW,
    const float* __restrict__ emb, const float* __restrict__ tem,
    u16* __restrict__ A1, u16* __restrict__ Wc,
    u16* __restrict__ A2, float* __restrict__ tsum) {
  const int blk = blockIdx.x;
  const int t = threadIdx.x;
  if (blk < PREP_ROWS) {               // ---- A1 / Wc rows (2048 f32 -> bf16, + 64 K-ext)
    const int row = blk * 2 + (t >> 8);
    const int tt = t & 255;
    const float* src;
    u16* orow;
    if (row < M1) { src = rf + (size_t)row * KIN; orow = A1 + (size_t)row * KA; }
    else {
      const int n = row - M1;
      src = (n < GG) ? (relW + (size_t)n * KIN) : (temW + (size_t)(n - GG) * KIN);
      orow = Wc + (size_t)n * KA;
    }
    const v4f* p = (const v4f*)src;
    v4f a = __builtin_nontemporal_load(p + 2 * tt);
    v4f b = __builtin_nontemporal_load(p + 2 * tt + 1);
    v8s v;
    v[0] = (short)f2bf(a[0]); v[1] = (short)f2bf(a[1]);
    v[2] = (short)f2bf(a[2]); v[3] = (short)f2bf(a[3]);
    v[4] = (short)f2bf(b[0]); v[5] = (short)f2bf(b[1]);
    v[6] = (short)f2bf(b[2]); v[7] = (short)f2bf(b[3]);
    *(v8s*)(orow + tt * 8) = v;
    if (tt < 64) {                     // K-extension columns
      float sval = 0.f;
      if (row < M1) {                  // S[m,l] = count(idx==l+1)/msum
        const int* rp = rel + (size_t)row * 20;
        int cnt = 0, ms = 0;
#pragma unroll
        for (int j = 0; j < 20; ++j) { int ix = rp[j]; cnt += (ix == tt + 1); ms += (ix > 0); }
        if (tt < 52 && ms > 0) sval = (float)cnt / (float)ms;
      } else {
        const int n = row - M1;
        if (n < GG && tt < 52) sval = emb[(size_t)(tt + 1) * GG + n];
      }
      orow[KIN + tt] = f2bf(sval);
    }
    return;
  }
  // ---- casta2: tem_feats -> A2 [32][640][576] bf16 + row sums (8 rows/block)
  const int w = t >> 6, l = t & 63;
  const int row = (blk - PREP_ROWS) * 8 + w;     // [32][640]
  const int b = row / M2, i = row % M2;
  u16* orow = A2 + (size_t)row * K2P;
  v8s z = {0, 0, 0, 0, 0, 0, 0, 0};
  if (i >= FO) {
    *(v8s*)(orow + l * 8) = z;
    if (l < 8) *(v8s*)(orow + (64 + l) * 8) = z;
    return;
  }
  const float* srow = tem + ((size_t)b * FO + i) * FO;
  float s = 0.f;
  {
    v4f a = __builtin_nontemporal_load((const v4f*)(srow + 8 * l));
    v4f bb = __builtin_nontemporal_load((const v4f*)(srow + 8 * l + 4));
    s += a[0] + a[1] + a[2] + a[3] + bb[0] + bb[1] + bb[2] + bb[3];
    v8s v;
    v[0] = (short)f2bf(a[0]); v[1] = (short)f2bf(a[1]);
    v[2] = (short)f2bf(a[2]); v[3] = (short)f2bf(a[3]);
    v[4] = (short)f2bf(bb[0]); v[5] = (short)f2bf(bb[1]);
    v[6] = (short)f2bf(bb[2]); v[7] = (short)f2bf(bb[3]);
    *(v8s*)(orow + l * 8) = v;
  }
  if (l < 8) {
    if (l == 0) {
      v4f a = __builtin_nontemporal_load((const v4f*)(srow + 512));
      v4f bb = __builtin_nontemporal_load((const v4f*)(srow + 516));
      s += a[0] + a[1] + a[2] + a[3] + bb[0] + bb[1] + bb[2] + bb[3];
      v8s v;
      v[0] = (short)f2bf(a[0]); v[1] = (short)f2bf(a[1]);
      v[2] = (short)f2bf(a[2]); v[3] = (short)f2bf(a[3]);
      v[4] = (short)f2bf(bb[0]); v[5] = (short)f2bf(bb[1]);
      v[6] = (short)f2bf(bb[2]); v[7] = (short)f2bf(bb[3]);
      *(v8s*)(orow + 512) = v;
    } else {
      *(v8s*)(orow + (64 + l) * 8) = z;
    }
  }
#pragma unroll
  for (int off = 32; off > 0; off >>= 1) s += __shfl_down(s, off);
  if (l == 0) tsum[(size_t)b * FO + i] = s;
}

// ---------- GEMM1: [16640x2112]x[2112x1024] bf16 MFMA, 256x128 tile ----------
// (R3-proven version: 113-118 us) 512 threads / 8 waves (4m x 2n, wave 64x64).
// BK=32; 3 LDS buffers of 24KB, depth-2 counted-vmcnt pipeline. Grid 520 =
// 65 mt x 8 nt, XCD-chunked swizzle.
#define G1_STAGE(DST)                                                                            \
  do {                                                                                           \
    u16* dst_ = smem + (DST);                                                                    \
    __builtin_amdgcn_global_load_lds((const __attribute__((address_space(1))) void*)ga0,         \
        (__attribute__((address_space(3))) void*)(dst_ + lofA0), 16, 0, 0);                      \
    __builtin_amdgcn_global_load_lds((const __attribute__((address_space(1))) void*)ga1,         \
        (__attribute__((address_space(3))) void*)(dst_ + lofA1), 16, 0, 0);                      \
    __builtin_amdgcn_global_load_lds((const __attribute__((address_space(1))) void*)gb0,         \
        (__attribute__((address_space(3))) void*)(dst_ + lofB0), 16, 0, 0);                      \
    ga0 += 32; ga1 += 32; gb0 += 32;                                                             \
  } while (0)

#define G1_COMPUTE(CB)                                                                           \
  do {                                                                                           \
    const u16* As_ = smem + (CB) * 12288;                                                        \
    const u16* Bs_ = As_ + 8192;                                                                 \
    v8s af[4], bf[4];                                                                            \
    _Pragma("unroll") for (int t4 = 0; t4 < 4; ++t4) {                                           \
      const int ra = wm * 64 + t4 * 16 + r16;                                                    \
      const int rb = wn * 64 + t4 * 16 + r16;                                                    \
      af[t4] = *(const v8s*)&As_[ra * 32 + ((quad ^ ((ra >> 1) & 3)) * 8)];                      \
      bf[t4] = *(const v8s*)&Bs_[rb * 32 + ((quad ^ ((rb >> 1) & 3)) * 8)];                      \
    }                                                                                            \
    _Pragma("unroll") for (int mtt = 0; mtt < 4; ++mtt)                                          \
      _Pragma("unroll") for (int ntt = 0; ntt < 4; ++ntt)                                        \
        acc[mtt][ntt] =                                                                          \
            __builtin_amdgcn_mfma_f32_16x16x32_bf16(af[mtt], bf[ntt], acc[mtt][ntt], 0, 0, 0);   \
  } while (0)

__global__ __launch_bounds__(512, 4) void gemm1_kernel(
    const u16* __restrict__ A, const u16* __restrict__ Wc,
    const float* __restrict__ rel_b, const float* __restrict__ tem_b,
    const float* __restrict__ bn_w, const float* __restrict__ bn_b,
    const float* __restrict__ bn_rm, const float* __restrict__ bn_rv,
    float* __restrict__ out, u16* __restrict__ BT) {
  __shared__ u16 smem[36864];                     // 72KB: 3 bufs x (A 16KB | B 8KB); epi reuses 33.8KB
  const int tid = threadIdx.x;
  const int lane = tid & 63;
  const int wv = tid >> 6, wm = wv >> 1, wn = wv & 1;   // 4m x 2n waves of 64x64
  // XCD-chunked bijective swizzle: 520 % 8 == 0 -> wgid = (id%8)*65 + id/8
  const int id = blockIdx.x;
  const int wgid = (id & 7) * 65 + (id >> 3);
  const int mt = wgid >> 3, nt = wgid & 7;        // 65 x 8
  const int m0 = mt * 256, n0 = nt * 128;
  const int quad = lane >> 4, r16 = lane & 15;

  // staging: chunk (row r, slot sl) holds global chunk c = sl ^ ((r>>1)&3)
  const u16 *ga0, *ga1, *gb0;
  {
    const int r0 = tid >> 2, sl0 = tid & 3;       // A rows 0..127
    ga0 = A + (size_t)(m0 + r0) * KA + (sl0 ^ ((r0 >> 1) & 3)) * 8;
    const int r1 = 128 + (tid >> 2);              // A rows 128..255
    ga1 = A + (size_t)(m0 + r1) * KA + (sl0 ^ ((r1 >> 1) & 3)) * 8;
    gb0 = Wc + (size_t)(n0 + r0) * KA + (sl0 ^ ((r0 >> 1) & 3)) * 8;   // B rows 0..127
  }
  const int lofA0 = wv * 512;                     // u16 offsets within buffer
  const int lofA1 = 4096 + wv * 512;
  const int lofB0 = 8192 + wv * 512;

  v4f acc[4][4];
#pragma unroll
  for (int i = 0; i < 4; ++i)
#pragma unroll
    for (int j = 0; j < 4; ++j) { v4f z = {0.f, 0.f, 0.f, 0.f}; acc[i][j] = z; }

  // prologue: stage K-tiles 0,1 into buffers 0,1 (6 loads in flight)
  G1_STAGE(0);
  G1_STAGE(12288);

  int cb = 0, nb = 2;                             // compute buf / next stage buf
  for (int t = 0; t < 64; ++t) {                  // tiles 0..63; stages tiles 2..65
    G1_STAGE(nb * 12288);                         // 9 loads in flight
    asm volatile("s_waitcnt vmcnt(6)" ::: "memory");  // tile t's 3 loads landed
    __builtin_amdgcn_s_barrier();                 // ...for every wave
    G1_COMPUTE(cb);
    asm volatile("s_waitcnt lgkmcnt(0)" ::: "memory");  // my ds_reads of buf cb done
    __builtin_amdgcn_s_barrier();                 // everyone done reading buf cb
    cb = (cb == 2) ? 0 : cb + 1;
    nb = (nb == 2) ? 0 : nb + 1;
  }
  {                                               // tiles 64, 65
    const int cb1 = (cb == 2) ? 0 : cb + 1;
    asm volatile("s_waitcnt vmcnt(3)" ::: "memory");
    __builtin_amdgcn_s_barrier();
    G1_COMPUTE(cb);
    asm volatile("s_waitcnt vmcnt(0) lgkmcnt(0)" ::: "memory");
    __builtin_amdgcn_s_barrier();
    G1_COMPUTE(cb1);
  }

  if (n0 < GG) {        // ---- rel half: +bias, tanh, BN -> out
#pragma unroll
    for (int mtt = 0; mtt < 4; ++mtt) {
      const int mb = m0 + wm * 64 + mtt * 16 + quad * 4;
      const int bb = mb / FO;
      const int fo0 = mb - bb * FO;               // quad never crosses batch (4 | FO)
      float inv[4], rm[4], bofs[4];
#pragma unroll
      for (int r = 0; r < 4; ++r) {
        const int fo = fo0 + r;
        inv[r] = bn_w[fo] * rsqrtf(bn_rv[fo] + 1e-5f);
        rm[r] = bn_rm[fo]; bofs[r] = bn_b[fo];
      }
#pragma unroll
      for (int ntt = 0; ntt < 4; ++ntt) {
        const int n = n0 + wn * 64 + ntt * 16 + r16;
        const float rbn = rel_b[n];
#pragma unroll
        for (int r = 0; r < 4; ++r) {
          float val = (fast_tanh(acc[mtt][ntt][r] + rbn) - rm[r]) * inv[r] + bofs[r];
          __builtin_nontemporal_store(val, out + (size_t)(mb + r) * N1 + n);
        }
      }
    }
  } else {              // ---- tem half: +bias -> bf16 -> LDS transpose -> BT (2 phases)
    __syncthreads();    // all waves done with K-loop LDS (reused as transpose buffer)
#pragma unroll
    for (int p = 0; p < 2; ++p) {
      if (p) __syncthreads();                     // phase0 readers done
      if (wn == p) {                              // 4 writer waves (wm 0..3)
#pragma unroll
        for (int mtt = 0; mtt < 4; ++mtt) {
          const int il = wm * 64 + mtt * 16 + quad * 4;   // 0..255
#pragma unroll
          for (int ntt = 0; ntt < 4; ++ntt) {
            const int gl = ntt * 16 + r16;        // local g row 0..63
            const float tb = tem_b[(n0 - GG) + p * 64 + gl];
            ushort4 w;
            w.x = f2bf(acc[mtt][ntt][0] + tb);
            w.y = f2bf(acc[mtt][ntt][1] + tb);
            w.z = f2bf(acc[mtt][ntt][2] + tb);
            w.w = f2bf(acc[mtt][ntt][3] + tb);
            *(ushort4*)&smem[gl * 264 + il] = w;  // [64 g][256 i + 8 pad]
          }
        }
      }
      __syncthreads();
      // 64 g-rows x 256 i: 4 passes x (16 g x 32 chunks), 512B contiguous stores
#pragma unroll
      for (int pass = 0; pass < 4; ++pass) {
        const int gl = pass * 16 + (tid >> 5);    // 0..63
        const int ch = tid & 31;
        const int m = m0 + ch * 8;
        const int b1 = m / FO;                    // 8-runs never cross b (520 % 8 == 0)
        const int i1 = m - b1 * FO;
        v8s val = *(const v8s*)&smem[gl * 264 + ch * 8];
        const int g = (n0 - GG) + p * 64 + gl;
        *(v8s*)(BT + ((size_t)(b1 * GG + g)) * K2P + i1) = val;
      }
    }
  }
}

// ---------- GEMM2: batched [640x576]x[576x512], 128x128 tiles, depth-2 pipeline ----------
#define G2_STAGE(DST)                                                                            \
  do {                                                                                           \
    u16* dst_ = smem + (DST);                                                                    \
    __builtin_amdgcn_global_load_lds((const __attribute__((address_space(1))) void*)ga0,         \
        (__attribute__((address_space(3))) void*)(dst_ + lofA0), 16, 0, 0);                      \
    __builtin_amdgcn_global_load_lds((const __attribute__((address_space(1))) void*)gb0,         \
        (__attribute__((address_space(3))) void*)(dst_ + lofB0), 16, 0, 0);                      \
    __builtin_amdgcn_global_load_lds((const __attribute__((address_space(1))) void*)ga1,         \
        (__attribute__((address_space(3))) void*)(dst_ + lofA1), 16, 0, 0);                      \
    __builtin_amdgcn_global_load_lds((const __attribute__((address_space(1))) void*)gb1,         \
        (__attribute__((address_space(3))) void*)(dst_ + lofB1), 16, 0, 0);                      \
    ga0 += 32; gb0 += 32; ga1 += 32; gb1 += 32;                                                  \
  } while (0)

#define G2_COMPUTE(CB)                                                                           \
  do {                                                                                           \
    const u16* As_ = smem + (CB) * 8192;                                                         \
    const u16* Bs_ = As_ + 4096;                                                                 \
    v8s af[4], bf[4];                                                                            \
    _Pragma("unroll") for (int t4 = 0; t4 < 4; ++t4) {                                           \
      const int ra = wm * 64 + t4 * 16 + r16;                                                    \
      const int rb = wn * 64 + t4 * 16 + r16;                                                    \
      af[t4] = *(const v8s*)&As_[ra * 32 + ((quad ^ ((ra >> 1) & 3)) * 8)];                      \
      bf[t4] = *(const v8s*)&Bs_[rb * 32 + ((quad ^ ((rb >> 1) & 3)) * 8)];                      \
    }                                                                                            \
    _Pragma("unroll") for (int mtt = 0; mtt < 4; ++mtt)                                          \
      _Pragma("unroll") for (int ntt = 0; ntt < 4; ++ntt)                                        \
        acc[mtt][ntt] =                                                                          \
            __builtin_amdgcn_mfma_f32_16x16x32_bf16(af[mtt], bf[ntt], acc[mtt][ntt], 0, 0, 0);   \
  } while (0)

__global__ __launch_bounds__(256) void gemm2_kernel(
    const u16* __restrict__ A2, const u16* __restrict__ BT,
    const float* __restrict__ tsum,
    const float* __restrict__ bn_w, const float* __restrict__ bn_b,
    const float* __restrict__ bn_rm, const float* __restrict__ bn_rv,
    float* __restrict__ out) {
  __shared__ u16 smem[24576];                     // 48KB: 3 bufs
  const int tid = threadIdx.x;
  const int lane = tid & 63;
  const int wv = tid >> 6, wm = wv >> 1, wn = wv & 1;   // 2x2 waves of 64x64
  const int m0 = blockIdx.x * 128;                // 5 tiles over 640
  const int n0 = blockIdx.y * 128;                // 4 tiles over 512
  const int b = blockIdx.z;
  const u16* Ab = A2 + (size_t)b * M2 * K2P;
  const u16* Bb = BT + (size_t)b * GG * K2P;
  const int quad = lane >> 4, r16 = lane & 15;

  const u16 *ga0, *ga1, *gb0, *gb1;
  {
    const int r0 = tid >> 2, sl0 = tid & 3;
    const int c0 = sl0 ^ ((r0 >> 1) & 3);
    ga0 = Ab + (size_t)(m0 + r0) * K2P + c0 * 8;
    gb0 = Bb + (size_t)(n0 + r0) * K2P + c0 * 8;
    const int L1 = 256 + tid;
    const int r1 = L1 >> 2, sl1 = L1 & 3;
    const int c1 = sl1 ^ ((r1 >> 1) & 3);
    ga1 = Ab + (size_t)(m0 + r1) * K2P + c1 * 8;
    gb1 = Bb + (size_t)(n0 + r1) * K2P + c1 * 8;
  }
  const int lofA0 = wv * 512, lofA1 = 2048 + wv * 512;
  const int lofB0 = 4096 + wv * 512, lofB1 = 6144 + wv * 512;

  v4f acc[4][4];
#pragma unroll
  for (int i = 0; i < 4; ++i)
#pragma unroll
    for (int j = 0; j < 4; ++j) { v4f z = {0.f, 0.f, 0.f, 0.f}; acc[i][j] = z; }

  // prologue
  G2_STAGE(0);
  G2_STAGE(8192);

  int cb = 0, nb = 2;
  for (int t = 0; t < 16; ++t) {                  // tiles 0..15; stages 2..17 (18 total)
    G2_STAGE(nb * 8192);
    asm volatile("s_waitcnt vmcnt(8)" ::: "memory");
    __builtin_amdgcn_s_barrier();
    G2_COMPUTE(cb);
    asm volatile("s_waitcnt lgkmcnt(0)" ::: "memory");
    __builtin_amdgcn_s_barrier();
    cb = (cb == 2) ? 0 : cb + 1;
    nb = (nb == 2) ? 0 : nb + 1;
  }
  {                                               // tiles 16, 17
    const int cb1 = (cb == 2) ? 0 : cb + 1;
    asm volatile("s_waitcnt vmcnt(4)" ::: "memory");
    __builtin_amdgcn_s_barrier();
    G2_COMPUTE(cb);
    asm volatile("s_waitcnt vmcnt(0) lgkmcnt(0)" ::: "memory");
    __builtin_amdgcn_s_barrier();
    G2_COMPUTE(cb1);
  }

  // epilogue: tem half of out
#pragma unroll
  for (int mtt = 0; mtt < 4; ++mtt) {
    const int ibase = m0 + wm * 64 + mtt * 16 + quad * 4;
    if (ibase >= FO) continue;                    // padded rows (ibase%4==0, FO%4==0)
    float ts[4], inv[4], rm[4], bofs[4];
#pragma unroll
    for (int r = 0; r < 4; ++r) {
      const int i = ibase + r;
      ts[r] = 1.f / tsum[(size_t)b * FO + i];
      inv[r] = bn_w[i] * rsqrtf(bn_rv[i] + 1e-5f);
      rm[r] = bn_rm[i]; bofs[r] = bn_b[i];
    }
#pragma unroll
    for (int ntt = 0; ntt < 4; ++ntt) {
      const int g = n0 + wn * 64 + ntt * 16 + r16;
#pragma unroll
      for (int r = 0; r < 4; ++r) {
        float val = (fast_tanh(acc[mtt][ntt][r] * ts[r]) - rm[r]) * inv[r] + bofs[r];
        __builtin_nontemporal_store(val, out + ((size_t)(b * FO + (ibase + r))) * N1 + GG + g);
      }
    }
  }
}

extern "C" void kernel_launch(void* const* d_in, const int* in_sizes, int n_in,
                              void* d_out, int out_size, void* d_ws, size_t ws_size,
                              hipStream_t stream) {
  const float* region_feats = (const float*)d_in[0];
  // d_in[1] region_masks: unused by reference
  const int* rel_feats = (const int*)d_in[2];
  const float* tem_feats = (const float*)d_in[3];
  const float* rel_W = (const float*)d_in[4];
  const float* rel_b = (const float*)d_in[5];
  const float* rel_emb = (const float*)d_in[6];
  const float* tem_W = (const float*)d_in[7];
  const float* tem_b = (const float*)d_in[8];
  const float* bn_w = (const float*)d_in[9];
  const float* bn_b = (const float*)d_in[10];
  const float* bn_rm = (const float*)d_in[11];
  const float* bn_rv = (const float*)d_in[12];
  float* out = (float*)d_out;

  // Workspace layout: total 117.1 MB
  char* base = (char*)d_ws;
  u16* A1 = (u16*)base;                                   // [16640][2112] bf16 : 70,287,360
  u16* Wc = (u16*)(base + 70287360);                      // [1024][2112] bf16  :  4,325,376
  u16* A2 = (u16*)(base + 74612736);                      // [32][640][576] bf16: 23,592,960
  u16* BT = (u16*)(base + 98205696);                      // [32][512][576] bf16: 18,874,368
  float* tsum = (float*)(base + 117080064);               // [32*520] f32       :     66,560

  prep_all_kernel<<<PREP_ROWS + 2560, 512, 0, stream>>>(
      region_feats, rel_feats, rel_W, tem_W, rel_emb, tem_feats, A1, Wc, A2, tsum);
  gemm1_kernel<<<520, 512, 0, stream>>>(A1, Wc, rel_b, tem_b,
                                        bn_w, bn_b, bn_rm, bn_rv, out, BT);
  gemm2_kernel<<<dim3(5, 4, 32), 256, 0, stream>>>(A2, BT, tsum,
                                                   bn_w, bn_b, bn_rm, bn_rv, out);
}